// Round 3
// baseline (106.118 us; speedup 1.0000x reference)
//
#include <hip/hip_runtime.h>
#include <stdint.h>
#include <math.h>

typedef __attribute__((ext_vector_type(8))) short bf16x8;
typedef __attribute__((ext_vector_type(4))) float f32x4;

#define HQ 2048
#define HK 2048
#define NH 8
#define ND 32
#define NC 256

union U8 { uint32_t u[4]; bf16x8 v; };

__device__ __forceinline__ uint16_t f2bf(float f) {
  uint32_t u = __float_as_uint(f);
  u += 0x7FFFu + ((u >> 16) & 1u);   // RNE
  return (uint16_t)(u >> 16);
}
__device__ __forceinline__ uint32_t pack2bf(float a, float b) {
  return (uint32_t)f2bf(a) | ((uint32_t)f2bf(b) << 16);
}
// 64B rows (32 bf16), 4 pieces of 16B (LDS swizzles used by proj/outproj only)
__device__ __forceinline__ int swz64(int row, int piece) {
  int s = (((row >> 3) & 1) << 1) | ((row >> 1) & 1);
  return row * 64 + ((piece ^ s) << 4);
}
__device__ __forceinline__ f32x4 mfma32(bf16x8 a, bf16x8 b, f32x4 c) {
  return __builtin_amdgcn_mfma_f32_16x16x32_bf16(a, b, c, 0, 0, 0);
}

// ---------------- projections: q,k,v,g -----------------------------------
// grid 1024: bx&63 = Mblock(64), (bx>>6)&3 = Nblock(4), bx>>8 = proj id
__global__ __launch_bounds__(256) void proj_kernel(
    const float* __restrict__ qx, const float* __restrict__ kvx,
    const float* __restrict__ Wq, const float* __restrict__ Wk,
    const float* __restrict__ Wv, const float* __restrict__ Wg,
    const float* __restrict__ bg,
    uint16_t* __restrict__ q_p, uint16_t* __restrict__ k_p,
    uint16_t* __restrict__ v_p, float* __restrict__ g_ws)
{
  const int bx = blockIdx.x;
  const int Mb = bx & 63, Nb = (bx >> 6) & 3, p = bx >> 8;
  const int Mbase = Mb * 64, Nbase = Nb * 64;
  const float* X = (p == 0 || p == 3) ? qx : kvx;
  const float* W = (p == 0) ? Wq : (p == 1) ? Wk : (p == 2) ? Wv : Wg;

  __shared__ __align__(16) uint16_t smem[4096]; // 8KB: X tile | W tile
  uint16_t* sX = smem;
  uint16_t* sW = smem + 2048;

  const int tid = threadIdx.x;
  const int l = tid & 63, w = tid >> 6;
  const int qq = l & 15, g = l >> 4;
  const int row = tid >> 2, gp = tid & 3;

  f32x4 acc[4] = {};

  for (int ks = 0; ks < 8; ++ks) {
    const float* xs = X + (size_t)(Mbase + row) * 256 + ks * 32 + gp * 8;
    f32x4 x0 = *(const f32x4*)xs;
    f32x4 x1 = *(const f32x4*)(xs + 4);
    const float* ws_ = W + (size_t)(Nbase + row) * 256 + ks * 32 + gp * 8;
    f32x4 w0 = *(const f32x4*)ws_;
    f32x4 w1 = *(const f32x4*)(ws_ + 4);
    U8 ux, uw;
    ux.u[0] = pack2bf(x0[0], x0[1]); ux.u[1] = pack2bf(x0[2], x0[3]);
    ux.u[2] = pack2bf(x1[0], x1[1]); ux.u[3] = pack2bf(x1[2], x1[3]);
    uw.u[0] = pack2bf(w0[0], w0[1]); uw.u[1] = pack2bf(w0[2], w0[3]);
    uw.u[2] = pack2bf(w1[0], w1[1]); uw.u[3] = pack2bf(w1[2], w1[3]);
    __syncthreads();
    *(bf16x8*)((char*)sX + swz64(row, gp)) = ux.v;
    *(bf16x8*)((char*)sW + swz64(row, gp)) = uw.v;
    __syncthreads();
    bf16x8 a = *(bf16x8*)((char*)sX + swz64(w * 16 + qq, g));
#pragma unroll
    for (int nf = 0; nf < 4; ++nf) {
      bf16x8 bb = *(bf16x8*)((char*)sW + swz64(nf * 16 + qq, g));
      acc[nf] = mfma32(a, bb, acc[nf]);
    }
  }

  if (p == 2) {
    // transpose epilogue -> v_p[B,H,D,K]
    __syncthreads();
#pragma unroll
    for (int nf = 0; nf < 4; ++nf) {
      int n_loc = nf * 16 + qq;
#pragma unroll
      for (int r = 0; r < 4; ++r) {
        int m_loc = w * 16 + 4 * g + r;
        int byte = n_loc * 128 + ((((m_loc >> 3) ^ (n_loc & 7)) << 4)) + (m_loc & 7) * 2;
        *(uint16_t*)((char*)smem + byte) = f2bf(acc[nf][r]);
      }
    }
    __syncthreads();
    const int n_loc = tid >> 2, mp = tid & 3;
    const int ng = Nbase + n_loc;
    const int hh = ng >> 5, dd = ng & 31;
    const int bb_ = Mbase >> 11;
#pragma unroll
    for (int jj = 0; jj < 2; ++jj) {
      int piece = mp * 2 + jj;
      bf16x8 vv = *(bf16x8*)((char*)smem + n_loc * 128 + ((piece ^ (n_loc & 7)) << 4));
      int seq = (Mbase & 2047) + piece * 8;
      *(bf16x8*)(v_p + ((size_t)(bb_ * NH + hh) * ND + dd) * (size_t)HK + seq) = vv;
    }
    return;
  }

#pragma unroll
  for (int nf = 0; nf < 4; ++nf) {
    int n = Nbase + nf * 16 + qq;
#pragma unroll
    for (int r = 0; r < 4; ++r) {
      int m = Mbase + w * 16 + 4 * g + r;
      float val = acc[nf][r];
      if (p == 0) {
        val *= 0.17677669529663687f; // 1/sqrt(32)
        int bb_ = m >> 11, seq = m & 2047, hh = n >> 5, dd = n & 31;
        q_p[((size_t)(bb_ * NH + hh) * HQ + seq) * ND + dd] = f2bf(val);
      } else if (p == 1) {
        int bb_ = m >> 11, seq = m & 2047, hh = n >> 5, dd = n & 31;
        k_p[((size_t)(bb_ * NH + hh) * HK + seq) * ND + dd] = f2bf(val);
      } else { // p == 3 : gate
        g_ws[(size_t)m * NC + n] = 1.f / (1.f + __expf(-(val + bg[n])));
      }
    }
  }
}

// ---------------- fused attention -----------------------------------------
// grid 512 x 512 threads: bx&1 = b, (bx>>1)&7 = h, bx>>4 = q-tile (64 rows)
// NO LDS / NO barriers in the main loop: K,V fragments are loaded directly
// from global in MFMA fragment layout (K tile = 4KB, identical addresses for
// all waves -> L1-resident). Waves free-run; only bias_pair (the HBM stream)
// is register-prefetched one iteration ahead. Halves (kt 0-15 / 16-31) merge
// via LDS in the epilogue.
__global__ __launch_bounds__(512, 4) void attn_kernel(
    const uint16_t* __restrict__ q_p, const uint16_t* __restrict__ k_p,
    const uint16_t* __restrict__ v_p, const float* __restrict__ bias_mask,
    const float* __restrict__ bias_pair, const float* __restrict__ g_ws,
    uint16_t* __restrict__ o_g)
{
  const int bx = blockIdx.x;
  const int b = bx & 1, h = (bx >> 1) & 7, qt = bx >> 4;
  const int bh = b * NH + h;

  __shared__ float mb[2304];   // 9216B: merge + transpose buffer (epilogue only)

  const int tid = threadIdx.x;
  const int l = tid & 63, w = tid >> 6;
  const int wq = w & 3, half = tid >> 8;   // half == w>>2
  const int qq = l & 15, g = l >> 4;
  const int q_glob = qt * 64 + wq * 16 + qq;

  // Q B-fragment: B[d, q] = q[q, d]; lane: q = l&15, d = g*8..+7  (hoisted)
  bf16x8 qf = *(const bf16x8*)(q_p + ((size_t)bh * HQ + q_glob) * ND + g * 8);

  f32x4 o0 = {}, o1 = {};
  float m_run = -1e30f, l_run = 0.f;

  const float* bp_base = bias_pair + ((size_t)h * HQ + q_glob) * (size_t)HK;
  const float* bm_base = bias_mask + (size_t)b * HK;
  const uint16_t* kbase_p = k_p + (size_t)bh * HK * ND;
  const uint16_t* vbase_p = v_p + (size_t)bh * ND * (size_t)HK;

  // QK A-fragment row permutation (makes P layout == PV B-fragment layout)
  const int kr0 = 8 * (qq >> 2) + (qq & 3);

  // ---- prologue: prefetch bias for t = 0 ----
  const int kt0 = half * 16;
  f32x4 bpc[4];
#pragma unroll
  for (int F = 0; F < 4; ++F)
    bpc[F] = *(const f32x4*)(bp_base + kt0 * 64 + 32 * (F >> 1) + 8 * g + 4 * (F & 1));

#pragma unroll 1
  for (int t = 0; t < 16; ++t) {
    const int kt = half * 16 + t;
    const size_t krow_base = (size_t)(kt * 64) * ND;

    // K fragments (direct, fragment layout): 4 x 16B/lane
    bf16x8 af0 = *(const bf16x8*)(kbase_p + krow_base + (size_t)(kr0)      * ND + g * 8);
    bf16x8 af1 = *(const bf16x8*)(kbase_p + krow_base + (size_t)(kr0 + 4)  * ND + g * 8);
    bf16x8 af2 = *(const bf16x8*)(kbase_p + krow_base + (size_t)(kr0 + 32) * ND + g * 8);
    bf16x8 af3 = *(const bf16x8*)(kbase_p + krow_base + (size_t)(kr0 + 36) * ND + g * 8);
    // V fragments (direct): rows d=qq and d=16+qq, col chunks (4c+g)*8
    const uint16_t* v0p = vbase_p + (size_t)qq * HK + kt * 64;
    const uint16_t* v1p = vbase_p + (size_t)(16 + qq) * HK + kt * 64;
    bf16x8 va00 = *(const bf16x8*)(v0p + g * 8);
    bf16x8 va01 = *(const bf16x8*)(v0p + (4 + g) * 8);
    bf16x8 va10 = *(const bf16x8*)(v1p + g * 8);
    bf16x8 va11 = *(const bf16x8*)(v1p + (4 + g) * 8);

    // prefetch bias for t+1 (consumed a full iteration later)
    const int tn = (t < 15) ? t + 1 : 15;
    const int ktn64 = (half * 16 + tn) * 64;
    f32x4 bpn[4];
#pragma unroll
    for (int F = 0; F < 4; ++F)
      bpn[F] = *(const f32x4*)(bp_base + ktn64 + 32 * (F >> 1) + 8 * g + 4 * (F & 1));

    // S^T = mfma(K_perm, Q)
    f32x4 z = {};
    f32x4 s0 = mfma32(af0, qf, z);
    f32x4 s1 = mfma32(af1, qf, z);
    f32x4 s2 = mfma32(af2, qf, z);
    f32x4 s3 = mfma32(af3, qf, z);

    // biases (k index for frag F, reg r: kt*64 + 32(F>>1) + 8g + 4(F&1) + r)
    const int kt64 = kt * 64;
    f32x4 bm0 = *(const f32x4*)(bm_base + kt64 + 8 * g);
    f32x4 bm1 = *(const f32x4*)(bm_base + kt64 + 8 * g + 4);
    f32x4 bm2 = *(const f32x4*)(bm_base + kt64 + 32 + 8 * g);
    f32x4 bm3 = *(const f32x4*)(bm_base + kt64 + 32 + 8 * g + 4);
#pragma unroll
    for (int r = 0; r < 4; ++r) {
      s0[r] += bpc[0][r] + bm0[r];
      s1[r] += bpc[1][r] + bm1[r];
      s2[r] += bpc[2][r] + bm2[r];
      s3[r] += bpc[3][r] + bm3[r];
    }
    // tree max
    float mx0 = fmaxf(fmaxf(s0[0], s0[1]), fmaxf(s0[2], s0[3]));
    float mx1 = fmaxf(fmaxf(s1[0], s1[1]), fmaxf(s1[2], s1[3]));
    float mx2 = fmaxf(fmaxf(s2[0], s2[1]), fmaxf(s2[2], s2[3]));
    float mx3 = fmaxf(fmaxf(s3[0], s3[1]), fmaxf(s3[2], s3[3]));
    float mloc = fmaxf(fmaxf(mx0, mx1), fmaxf(mx2, mx3));
    mloc = fmaxf(mloc, __shfl_xor(mloc, 16, 64));
    mloc = fmaxf(mloc, __shfl_xor(mloc, 32, 64));
    float m_new = fmaxf(m_run, mloc);
    float alpha = __expf(m_run - m_new);

    uint32_t pbk[4][2];
    float ps0, ps1, ps2, ps3;
    {
      float p0 = __expf(s0[0] - m_new), p1 = __expf(s0[1] - m_new);
      float p2 = __expf(s0[2] - m_new), p3 = __expf(s0[3] - m_new);
      ps0 = (p0 + p1) + (p2 + p3);
      pbk[0][0] = pack2bf(p0, p1); pbk[0][1] = pack2bf(p2, p3);
      p0 = __expf(s1[0] - m_new); p1 = __expf(s1[1] - m_new);
      p2 = __expf(s1[2] - m_new); p3 = __expf(s1[3] - m_new);
      ps1 = (p0 + p1) + (p2 + p3);
      pbk[1][0] = pack2bf(p0, p1); pbk[1][1] = pack2bf(p2, p3);
      p0 = __expf(s2[0] - m_new); p1 = __expf(s2[1] - m_new);
      p2 = __expf(s2[2] - m_new); p3 = __expf(s2[3] - m_new);
      ps2 = (p0 + p1) + (p2 + p3);
      pbk[2][0] = pack2bf(p0, p1); pbk[2][1] = pack2bf(p2, p3);
      p0 = __expf(s3[0] - m_new); p1 = __expf(s3[1] - m_new);
      p2 = __expf(s3[2] - m_new); p3 = __expf(s3[3] - m_new);
      ps3 = (p0 + p1) + (p2 + p3);
      pbk[3][0] = pack2bf(p0, p1); pbk[3][1] = pack2bf(p2, p3);
    }
    float psum = (ps0 + ps1) + (ps2 + ps3);
    psum += __shfl_xor(psum, 16, 64);
    psum += __shfl_xor(psum, 32, 64);
    l_run = l_run * alpha + psum;
    m_run = m_new;
#pragma unroll
    for (int r = 0; r < 4; ++r) { o0[r] *= alpha; o1[r] *= alpha; }

    // O^T += V^T . P^T  (two k-chunks of 32, two d-halves)
    U8 bu0, bu1;
    bu0.u[0] = pbk[0][0]; bu0.u[1] = pbk[0][1];
    bu0.u[2] = pbk[1][0]; bu0.u[3] = pbk[1][1];
    bu1.u[0] = pbk[2][0]; bu1.u[1] = pbk[2][1];
    bu1.u[2] = pbk[3][0]; bu1.u[3] = pbk[3][1];
    o0 = mfma32(va00, bu0.v, o0);
    o1 = mfma32(va10, bu0.v, o1);
    o0 = mfma32(va01, bu1.v, o0);
    o1 = mfma32(va11, bu1.v, o1);

#pragma unroll
    for (int F = 0; F < 4; ++F) bpc[F] = bpn[F];
  }

  // ---- epilogue: flash-merge half1 into half0, then /l, transpose, gate ----
  if (half == 1) {
    float* bq = mb + (wq * 16 + qq) * 36;
    if (g == 0) { bq[32] = m_run; bq[33] = l_run; }
#pragma unroll
    for (int r = 0; r < 4; ++r) {
      bq[4 * g + r]      = o0[r];
      bq[16 + 4 * g + r] = o1[r];
    }
  }
  __syncthreads();
  float o0f[4], o1f[4]; float inv = 0.f;
  if (half == 0) {
    const float* bq = mb + (wq * 16 + qq) * 36;
    float mB = bq[32], lB = bq[33];
    float mf = fmaxf(m_run, mB);
    float aA = __expf(m_run - mf), aB = __expf(mB - mf);
    inv = 1.f / (l_run * aA + lB * aB);
#pragma unroll
    for (int r = 0; r < 4; ++r) {
      o0f[r] = o0[r] * aA + bq[4 * g + r] * aB;
      o1f[r] = o1[r] * aA + bq[16 + 4 * g + r] * aB;
    }
  }
  __syncthreads();                           // merge reads done before overwrite
  if (half == 0) {
    float* se = mb + wq * 576;               // [16 q][36 d] per wave
#pragma unroll
    for (int r = 0; r < 4; ++r) {
      se[qq * 36 + 4 * g + r]      = o0f[r] * inv;   // d = 4g+r
      se[qq * 36 + 16 + 4 * g + r] = o1f[r] * inv;   // d = 16+4g+r
    }
  }
  __syncthreads();
  if (half == 0) {
    const int qrow = l >> 2, pc = l & 3;
    const float* sr = mb + wq * 576 + qrow * 36 + pc * 8;
    f32x4 x0 = *(const f32x4*)sr;
    f32x4 x1 = *(const f32x4*)(sr + 4);
    const int q_out = qt * 64 + wq * 16 + qrow;
    const float* gp_ = g_ws + ((size_t)b * HQ + q_out) * NC + h * ND + pc * 8;
    f32x4 g0 = *(const f32x4*)gp_;
    f32x4 g1 = *(const f32x4*)(gp_ + 4);
    U8 ou;
    ou.u[0] = pack2bf(x0[0] * g0[0], x0[1] * g0[1]);
    ou.u[1] = pack2bf(x0[2] * g0[2], x0[3] * g0[3]);
    ou.u[2] = pack2bf(x1[0] * g1[0], x1[1] * g1[1]);
    ou.u[3] = pack2bf(x1[2] * g1[2], x1[3] * g1[3]);
    *(bf16x8*)(o_g + ((size_t)b * HQ + q_out) * NC + h * ND + pc * 8) = ou.v;
  }
}

// ---------------- output projection ---------------------------------------
// grid 256: bx&63 = Mblock, bx>>6 = Nblock
__global__ __launch_bounds__(256) void outproj_kernel(
    const uint16_t* __restrict__ o_g, const float* __restrict__ Wo,
    const float* __restrict__ bo, float* __restrict__ out)
{
  const int bx = blockIdx.x;
  const int Mb = bx & 63, Nb = bx >> 6;
  const int Mbase = Mb * 64, Nbase = Nb * 64;
  __shared__ __align__(16) uint16_t smem2[4096];
  uint16_t* sA = smem2;
  uint16_t* sB = smem2 + 2048;
  const int tid = threadIdx.x;
  const int l = tid & 63, w = tid >> 6;
  const int qq = l & 15, g = l >> 4;
  const int row = tid >> 2, gp = tid & 3;
  f32x4 acc[4] = {};
  for (int ks = 0; ks < 8; ++ks) {
    bf16x8 av = *(const bf16x8*)(o_g + (size_t)(Mbase + row) * 256 + ks * 32 + gp * 8);
    const float* wsrc = Wo + (size_t)(Nbase + row) * 256 + ks * 32 + gp * 8;
    f32x4 w0 = *(const f32x4*)wsrc;
    f32x4 w1 = *(const f32x4*)(wsrc + 4);
    U8 uw;
    uw.u[0] = pack2bf(w0[0], w0[1]); uw.u[1] = pack2bf(w0[2], w0[3]);
    uw.u[2] = pack2bf(w1[0], w1[1]); uw.u[3] = pack2bf(w1[2], w1[3]);
    __syncthreads();
    *(bf16x8*)((char*)sA + swz64(row, gp)) = av;
    *(bf16x8*)((char*)sB + swz64(row, gp)) = uw.v;
    __syncthreads();
    bf16x8 a = *(bf16x8*)((char*)sA + swz64(w * 16 + qq, g));
#pragma unroll
    for (int nf = 0; nf < 4; ++nf) {
      bf16x8 bb = *(bf16x8*)((char*)sB + swz64(nf * 16 + qq, g));
      acc[nf] = mfma32(a, bb, acc[nf]);
    }
  }
#pragma unroll
  for (int nf = 0; nf < 4; ++nf) {
    int n = Nbase + nf * 16 + qq;
    float bias = bo[n];
#pragma unroll
    for (int r = 0; r < 4; ++r) {
      int m = Mbase + w * 16 + 4 * g + r;
      out[(size_t)m * NC + n] = acc[nf][r] + bias;
    }
  }
}

extern "C" void kernel_launch(void* const* d_in, const int* in_sizes, int n_in,
                              void* d_out, int out_size, void* d_ws, size_t ws_size,
                              hipStream_t stream) {
  (void)in_sizes; (void)n_in; (void)out_size; (void)ws_size;
  const float* qx        = (const float*)d_in[0];
  const float* kvx       = (const float*)d_in[1];
  const float* bias_mask = (const float*)d_in[2];
  const float* bias_pair = (const float*)d_in[3];
  const float* Wq        = (const float*)d_in[4];
  const float* Wk        = (const float*)d_in[5];
  const float* Wv        = (const float*)d_in[6];
  const float* Wo        = (const float*)d_in[7];
  const float* bo        = (const float*)d_in[8];
  const float* Wg        = (const float*)d_in[9];
  const float* bg        = (const float*)d_in[10];

  char* ws = (char*)d_ws;
  uint16_t* q_p  = (uint16_t*)(ws);                       // 2 MB
  uint16_t* k_p  = (uint16_t*)(ws + (2u << 20));          // 2 MB
  uint16_t* v_p  = (uint16_t*)(ws + (4u << 20));          // 2 MB  [B,H,D,K]
  float*    g_ws = (float*)   (ws + (6u << 20));          // 4 MB
  uint16_t* o_g  = (uint16_t*)(ws + (10u << 20));         // 2 MB
  float* out = (float*)d_out;

  proj_kernel<<<dim3(1024), dim3(256), 0, stream>>>(qx, kvx, Wq, Wk, Wv, Wg, bg,
                                                    q_p, k_p, v_p, g_ws);
  attn_kernel<<<dim3(512), dim3(512), 0, stream>>>(q_p, k_p, v_p, bias_mask,
                                                   bias_pair, g_ws, o_g);
  outproj_kernel<<<dim3(256), dim3(256), 0, stream>>>(o_g, Wo, bo, out);
}

// Round 4
// 74.628 us; speedup vs baseline: 1.4220x; 1.4220x over previous
//
#include <hip/hip_runtime.h>
#include <stdint.h>
#include <math.h>

typedef __attribute__((ext_vector_type(8))) short bf16x8;
typedef __attribute__((ext_vector_type(4))) float f32x4;

#define HQ 2048
#define HK 2048
#define NH 8
#define ND 32
#define NC 256

union U8 { uint32_t u[4]; bf16x8 v; };

__device__ __forceinline__ uint16_t f2bf(float f) {
  uint32_t u = __float_as_uint(f);
  u += 0x7FFFu + ((u >> 16) & 1u);   // RNE
  return (uint16_t)(u >> 16);
}
__device__ __forceinline__ uint32_t pack2bf(float a, float b) {
  return (uint32_t)f2bf(a) | ((uint32_t)f2bf(b) << 16);
}
// 64B rows (32 bf16), 4 pieces of 16B (used by proj/outproj LDS tiles)
__device__ __forceinline__ int swz64(int row, int piece) {
  int s = (((row >> 3) & 1) << 1) | ((row >> 1) & 1);
  return row * 64 + ((piece ^ s) << 4);
}
__device__ __forceinline__ f32x4 mfma32(bf16x8 a, bf16x8 b, f32x4 c) {
  return __builtin_amdgcn_mfma_f32_16x16x32_bf16(a, b, c, 0, 0, 0);
}
// async global->LDS DMA, 16B per lane; dst must be wave-uniform (HW: dst+lane*16)
__device__ __forceinline__ void dma16(const void* g, void* l) {
  __builtin_amdgcn_global_load_lds(
      (const __attribute__((address_space(1))) uint32_t*)g,
      (__attribute__((address_space(3))) uint32_t*)l, 16, 0, 0);
}

// ---------------- projections: q,k,v,g -----------------------------------
// grid 1024: bx&63 = Mblock(64), (bx>>6)&3 = Nblock(4), bx>>8 = proj id
__global__ __launch_bounds__(256) void proj_kernel(
    const float* __restrict__ qx, const float* __restrict__ kvx,
    const float* __restrict__ Wq, const float* __restrict__ Wk,
    const float* __restrict__ Wv, const float* __restrict__ Wg,
    const float* __restrict__ bg,
    uint16_t* __restrict__ q_p, uint16_t* __restrict__ k_p,
    uint16_t* __restrict__ v_p, float* __restrict__ g_ws)
{
  const int bx = blockIdx.x;
  const int Mb = bx & 63, Nb = (bx >> 6) & 3, p = bx >> 8;
  const int Mbase = Mb * 64, Nbase = Nb * 64;
  const float* X = (p == 0 || p == 3) ? qx : kvx;
  const float* W = (p == 0) ? Wq : (p == 1) ? Wk : (p == 2) ? Wv : Wg;

  __shared__ __align__(16) uint16_t smem[4096]; // 8KB: X tile | W tile
  uint16_t* sX = smem;
  uint16_t* sW = smem + 2048;

  const int tid = threadIdx.x;
  const int l = tid & 63, w = tid >> 6;
  const int qq = l & 15, g = l >> 4;
  const int row = tid >> 2, gp = tid & 3;

  f32x4 acc[4] = {};

  for (int ks = 0; ks < 8; ++ks) {
    const float* xs = X + (size_t)(Mbase + row) * 256 + ks * 32 + gp * 8;
    f32x4 x0 = *(const f32x4*)xs;
    f32x4 x1 = *(const f32x4*)(xs + 4);
    const float* ws_ = W + (size_t)(Nbase + row) * 256 + ks * 32 + gp * 8;
    f32x4 w0 = *(const f32x4*)ws_;
    f32x4 w1 = *(const f32x4*)(ws_ + 4);
    U8 ux, uw;
    ux.u[0] = pack2bf(x0[0], x0[1]); ux.u[1] = pack2bf(x0[2], x0[3]);
    ux.u[2] = pack2bf(x1[0], x1[1]); ux.u[3] = pack2bf(x1[2], x1[3]);
    uw.u[0] = pack2bf(w0[0], w0[1]); uw.u[1] = pack2bf(w0[2], w0[3]);
    uw.u[2] = pack2bf(w1[0], w1[1]); uw.u[3] = pack2bf(w1[2], w1[3]);
    __syncthreads();
    *(bf16x8*)((char*)sX + swz64(row, gp)) = ux.v;
    *(bf16x8*)((char*)sW + swz64(row, gp)) = uw.v;
    __syncthreads();
    bf16x8 a = *(bf16x8*)((char*)sX + swz64(w * 16 + qq, g));
#pragma unroll
    for (int nf = 0; nf < 4; ++nf) {
      bf16x8 bb = *(bf16x8*)((char*)sW + swz64(nf * 16 + qq, g));
      acc[nf] = mfma32(a, bb, acc[nf]);
    }
  }

  if (p == 2) {
    // transpose epilogue -> v_p[B,H,D,K]
    __syncthreads();
#pragma unroll
    for (int nf = 0; nf < 4; ++nf) {
      int n_loc = nf * 16 + qq;
#pragma unroll
      for (int r = 0; r < 4; ++r) {
        int m_loc = w * 16 + 4 * g + r;
        int byte = n_loc * 128 + ((((m_loc >> 3) ^ (n_loc & 7)) << 4)) + (m_loc & 7) * 2;
        *(uint16_t*)((char*)smem + byte) = f2bf(acc[nf][r]);
      }
    }
    __syncthreads();
    const int n_loc = tid >> 2, mp = tid & 3;
    const int ng = Nbase + n_loc;
    const int hh = ng >> 5, dd = ng & 31;
    const int bb_ = Mbase >> 11;
#pragma unroll
    for (int jj = 0; jj < 2; ++jj) {
      int piece = mp * 2 + jj;
      bf16x8 vv = *(bf16x8*)((char*)smem + n_loc * 128 + ((piece ^ (n_loc & 7)) << 4));
      int seq = (Mbase & 2047) + piece * 8;
      *(bf16x8*)(v_p + ((size_t)(bb_ * NH + hh) * ND + dd) * (size_t)HK + seq) = vv;
    }
    return;
  }

#pragma unroll
  for (int nf = 0; nf < 4; ++nf) {
    int n = Nbase + nf * 16 + qq;
#pragma unroll
    for (int r = 0; r < 4; ++r) {
      int m = Mbase + w * 16 + 4 * g + r;
      float val = acc[nf][r];
      if (p == 0) {
        val *= 0.17677669529663687f; // 1/sqrt(32)
        int bb_ = m >> 11, seq = m & 2047, hh = n >> 5, dd = n & 31;
        q_p[((size_t)(bb_ * NH + hh) * HQ + seq) * ND + dd] = f2bf(val);
      } else if (p == 1) {
        int bb_ = m >> 11, seq = m & 2047, hh = n >> 5, dd = n & 31;
        k_p[((size_t)(bb_ * NH + hh) * HK + seq) * ND + dd] = f2bf(val);
      } else { // p == 3 : gate
        g_ws[(size_t)m * NC + n] = 1.f / (1.f + __expf(-(val + bg[n])));
      }
    }
  }
}

// ---------------- fused attention -----------------------------------------
// grid 512 x 256 threads: bx&1 = b, (bx>>1)&7 = h, bx>>4 = q-tile (64 rows)
// Double-buffered global_load_lds DMA pipeline (counted vmcnt, raw barriers).
// Per iter each wave issues 6x1KB DMAs staging tile t+1 (K 4KB, V 4KB,
// bias_pair 16KB) with PRE-SWIZZLED global source addresses so all
// ds_read_b128 fragment reads hit the 2-lane/bank floor.
__global__ __launch_bounds__(256, 4) void attn_kernel(
    const uint16_t* __restrict__ q_p, const uint16_t* __restrict__ k_p,
    const uint16_t* __restrict__ v_p, const float* __restrict__ bias_mask,
    const float* __restrict__ bias_pair, const float* __restrict__ g_ws,
    uint16_t* __restrict__ o_g)
{
  const int bx = blockIdx.x;
  const int b = bx & 1, h = (bx >> 1) & 7, qt = bx >> 4;
  const int bh = b * NH + h;

  __shared__ __align__(16) char LDS[49152];
  char* sK = LDS;            // 2 x 4KB
  char* sV = LDS + 8192;     // 2 x 4KB
  char* sP = LDS + 16384;    // 2 x 16KB

  const int tid = threadIdx.x;
  const int l = tid & 63, wq = tid >> 6;
  const int qq = l & 15, g = l >> 4;
  const int q_glob = qt * 64 + wq * 16 + qq;

  // Q B-fragment (hoisted)
  bf16x8 qf = *(const bf16x8*)(q_p + ((size_t)bh * HQ + q_glob) * ND + g * 8);

  // ---- per-lane staging source addresses (pre-swizzled) ----
  // K tile: LDS slot order = fragment order: slot s=16F+qs -> k-row
  // 8*(qs>>2)+(qs&3)+4*(F&1)+32*(F>>1); 128B LDS rows hold 2 slots; chunk
  // index xor'd with (Lrow&7).
  const char* kSrc;
  {
    int B = wq * 1024 + l * 16;
    int Lr = B >> 7, q8 = l & 7;
    int hp = q8 ^ (Lr & 7);
    int half = hp >> 2, pc = hp & 3;
    int s = Lr * 2 + half, F = s >> 4, qs = s & 15;
    int krow = 8 * (qs >> 2) + (qs & 3) + (F & 1) * 4 + (F >> 1) * 32;
    kSrc = (const char*)(k_p + (size_t)bh * HK * ND) + krow * 64 + pc * 16;
  }
  // V tile: 32 rows x 128B, chunk ^= row&7
  const char* vSrc;
  {
    int B = wq * 1024 + l * 16;
    int d = B >> 7, q8 = l & 7;
    int pc = q8 ^ (d & 7);
    vSrc = (const char*)(v_p + (size_t)bh * ND * (size_t)HK) + (size_t)d * HK * 2 + pc * 16;
  }
  // bias_pair tile: 64 rows x 256B, chunk low3 ^= row&7
  const char* pSrc0; const char* pSrc1; const char* pSrc2; const char* pSrc3;
  {
    const char* bpBlk = (const char*)bias_pair + ((size_t)h * HQ + qt * 64) * (size_t)HK * 4;
    int q16 = l & 15;
#define BP_SRC(jj) ({ int row = (wq * 4 + (jj)) * 4 + (l >> 4); \
                      int pc = (q16 & 8) | ((q16 & 7) ^ (row & 7)); \
                      bpBlk + (size_t)row * HK * 4 + pc * 16; })
    pSrc0 = BP_SRC(0); pSrc1 = BP_SRC(1); pSrc2 = BP_SRC(2); pSrc3 = BP_SRC(3);
#undef BP_SRC
  }
  // wave-uniform LDS dst bases
  char* kDst = sK + wq * 1024;
  char* vDst = sV + wq * 1024;
  char* pDst = sP + wq * 4096;

  // ---- reader byte offsets (loop-invariant) ----
  int afOff[4], vaOff[4], bpOff[4];
#pragma unroll
  for (int F = 0; F < 4; ++F) {
    int Ls = 8 * F + (qq >> 1);
    afOff[F] = Ls * 128 + (((qq & 1) * 4 + g) ^ (qq >> 1)) * 16;
  }
#pragma unroll
  for (int hd = 0; hd < 2; ++hd)
#pragma unroll
    for (int c = 0; c < 2; ++c) {
      int d = hd * 16 + qq;
      vaOff[hd * 2 + c] = d * 128 + ((4 * c + g) ^ (d & 7)) * 16;
    }
#pragma unroll
  for (int F = 0; F < 4; ++F) {
    int piece = 8 * (F >> 1) + 2 * g + (F & 1);
    int row = wq * 16 + qq;
    bpOff[F] = row * 256 + ((piece & 8) | ((piece & 7) ^ (row & 7))) * 16;
  }

#define STAGE(tt, dbi) do { \
    dma16(kSrc + (size_t)(tt) * 4096, kDst + (dbi) * 4096); \
    dma16(vSrc + (size_t)(tt) * 128,  vDst + (dbi) * 4096); \
    dma16(pSrc0 + (size_t)(tt) * 256, pDst + (dbi) * 16384); \
    dma16(pSrc1 + (size_t)(tt) * 256, pDst + (dbi) * 16384 + 1024); \
    dma16(pSrc2 + (size_t)(tt) * 256, pDst + (dbi) * 16384 + 2048); \
    dma16(pSrc3 + (size_t)(tt) * 256, pDst + (dbi) * 16384 + 3072); \
  } while (0)

  f32x4 o0 = {}, o1 = {};
  float m_run = -1e30f, l_run = 0.f;
  const float* bm_base = bias_mask + (size_t)b * HK;

  STAGE(0, 0);

#pragma unroll 1
  for (int t = 0; t < 32; ++t) {
    const int bi = t & 1;
    if (t < 31) {
      STAGE(t + 1, bi ^ 1);
      asm volatile("s_waitcnt vmcnt(6)" ::: "memory");
    } else {
      asm volatile("s_waitcnt vmcnt(0)" ::: "memory");
    }
    __builtin_amdgcn_s_barrier();
    __builtin_amdgcn_sched_barrier(0);

    const char* bK = sK + bi * 4096;
    const char* bV = sV + bi * 4096;
    const char* bP = sP + bi * 16384;

    bf16x8 af0 = *(const bf16x8*)(bK + afOff[0]);
    bf16x8 af1 = *(const bf16x8*)(bK + afOff[1]);
    bf16x8 af2 = *(const bf16x8*)(bK + afOff[2]);
    bf16x8 af3 = *(const bf16x8*)(bK + afOff[3]);
    f32x4 z = {};
    f32x4 s0 = mfma32(af0, qf, z);
    f32x4 s1 = mfma32(af1, qf, z);
    f32x4 s2 = mfma32(af2, qf, z);
    f32x4 s3 = mfma32(af3, qf, z);

    f32x4 bp0 = *(const f32x4*)(bP + bpOff[0]);
    f32x4 bp1 = *(const f32x4*)(bP + bpOff[1]);
    f32x4 bp2 = *(const f32x4*)(bP + bpOff[2]);
    f32x4 bp3 = *(const f32x4*)(bP + bpOff[3]);
    const int kt64 = t * 64;
    f32x4 bm0 = *(const f32x4*)(bm_base + kt64 + 8 * g);
    f32x4 bm1 = *(const f32x4*)(bm_base + kt64 + 8 * g + 4);
    f32x4 bm2 = *(const f32x4*)(bm_base + kt64 + 32 + 8 * g);
    f32x4 bm3 = *(const f32x4*)(bm_base + kt64 + 32 + 8 * g + 4);
#pragma unroll
    for (int r = 0; r < 4; ++r) {
      s0[r] += bp0[r] + bm0[r];
      s1[r] += bp1[r] + bm1[r];
      s2[r] += bp2[r] + bm2[r];
      s3[r] += bp3[r] + bm3[r];
    }
    float mx0 = fmaxf(fmaxf(s0[0], s0[1]), fmaxf(s0[2], s0[3]));
    float mx1 = fmaxf(fmaxf(s1[0], s1[1]), fmaxf(s1[2], s1[3]));
    float mx2 = fmaxf(fmaxf(s2[0], s2[1]), fmaxf(s2[2], s2[3]));
    float mx3 = fmaxf(fmaxf(s3[0], s3[1]), fmaxf(s3[2], s3[3]));
    float mloc = fmaxf(fmaxf(mx0, mx1), fmaxf(mx2, mx3));
    mloc = fmaxf(mloc, __shfl_xor(mloc, 16, 64));
    mloc = fmaxf(mloc, __shfl_xor(mloc, 32, 64));
    float m_new = fmaxf(m_run, mloc);
    float alpha = __expf(m_run - m_new);

    uint32_t pbk[4][2];
    float ps0, ps1, ps2, ps3;
    {
      float p0 = __expf(s0[0] - m_new), p1 = __expf(s0[1] - m_new);
      float p2 = __expf(s0[2] - m_new), p3 = __expf(s0[3] - m_new);
      ps0 = (p0 + p1) + (p2 + p3);
      pbk[0][0] = pack2bf(p0, p1); pbk[0][1] = pack2bf(p2, p3);
      p0 = __expf(s1[0] - m_new); p1 = __expf(s1[1] - m_new);
      p2 = __expf(s1[2] - m_new); p3 = __expf(s1[3] - m_new);
      ps1 = (p0 + p1) + (p2 + p3);
      pbk[1][0] = pack2bf(p0, p1); pbk[1][1] = pack2bf(p2, p3);
      p0 = __expf(s2[0] - m_new); p1 = __expf(s2[1] - m_new);
      p2 = __expf(s2[2] - m_new); p3 = __expf(s2[3] - m_new);
      ps2 = (p0 + p1) + (p2 + p3);
      pbk[2][0] = pack2bf(p0, p1); pbk[2][1] = pack2bf(p2, p3);
      p0 = __expf(s3[0] - m_new); p1 = __expf(s3[1] - m_new);
      p2 = __expf(s3[2] - m_new); p3 = __expf(s3[3] - m_new);
      ps3 = (p0 + p1) + (p2 + p3);
      pbk[3][0] = pack2bf(p0, p1); pbk[3][1] = pack2bf(p2, p3);
    }
    float psum = (ps0 + ps1) + (ps2 + ps3);
    psum += __shfl_xor(psum, 16, 64);
    psum += __shfl_xor(psum, 32, 64);
    l_run = l_run * alpha + psum;
    m_run = m_new;
#pragma unroll
    for (int r = 0; r < 4; ++r) { o0[r] *= alpha; o1[r] *= alpha; }

    U8 bu0, bu1;
    bu0.u[0] = pbk[0][0]; bu0.u[1] = pbk[0][1];
    bu0.u[2] = pbk[1][0]; bu0.u[3] = pbk[1][1];
    bu1.u[0] = pbk[2][0]; bu1.u[1] = pbk[2][1];
    bu1.u[2] = pbk[3][0]; bu1.u[3] = pbk[3][1];
    bf16x8 va00 = *(const bf16x8*)(bV + vaOff[0]);
    bf16x8 va01 = *(const bf16x8*)(bV + vaOff[1]);
    bf16x8 va10 = *(const bf16x8*)(bV + vaOff[2]);
    bf16x8 va11 = *(const bf16x8*)(bV + vaOff[3]);
    o0 = mfma32(va00, bu0.v, o0);
    o1 = mfma32(va10, bu0.v, o1);
    o0 = mfma32(va01, bu1.v, o0);
    o1 = mfma32(va11, bu1.v, o1);

    __builtin_amdgcn_sched_barrier(0);
    __builtin_amdgcn_s_barrier();
  }
#undef STAGE

  // ---- epilogue: /l, LDS transpose, gate, coalesced bf16 store ----
  __syncthreads();
  float inv = 1.f / l_run;
  float* se = (float*)LDS + wq * 576;      // [16 q][36 d] per wave
#pragma unroll
  for (int r = 0; r < 4; ++r) {
    se[qq * 36 + 4 * g + r]      = o0[r] * inv;   // d = 4g+r
    se[qq * 36 + 16 + 4 * g + r] = o1[r] * inv;   // d = 16+4g+r
  }
  __syncthreads();
  {
    const int qrow = l >> 2, pc = l & 3;
    const float* sr = (float*)LDS + wq * 576 + qrow * 36 + pc * 8;
    f32x4 x0 = *(const f32x4*)sr;
    f32x4 x1 = *(const f32x4*)(sr + 4);
    const int q_out = qt * 64 + wq * 16 + qrow;
    const float* gp_ = g_ws + ((size_t)b * HQ + q_out) * NC + h * ND + pc * 8;
    f32x4 g0 = *(const f32x4*)gp_;
    f32x4 g1 = *(const f32x4*)(gp_ + 4);
    U8 ou;
    ou.u[0] = pack2bf(x0[0] * g0[0], x0[1] * g0[1]);
    ou.u[1] = pack2bf(x0[2] * g0[2], x0[3] * g0[3]);
    ou.u[2] = pack2bf(x1[0] * g1[0], x1[1] * g1[1]);
    ou.u[3] = pack2bf(x1[2] * g1[2], x1[3] * g1[3]);
    *(bf16x8*)(o_g + ((size_t)b * HQ + q_out) * NC + h * ND + pc * 8) = ou.v;
  }
}

// ---------------- output projection ---------------------------------------
// grid 256: bx&63 = Mblock, bx>>6 = Nblock
__global__ __launch_bounds__(256) void outproj_kernel(
    const uint16_t* __restrict__ o_g, const float* __restrict__ Wo,
    const float* __restrict__ bo, float* __restrict__ out)
{
  const int bx = blockIdx.x;
  const int Mb = bx & 63, Nb = bx >> 6;
  const int Mbase = Mb * 64, Nbase = Nb * 64;
  __shared__ __align__(16) uint16_t smem2[4096];
  uint16_t* sA = smem2;
  uint16_t* sB = smem2 + 2048;
  const int tid = threadIdx.x;
  const int l = tid & 63, w = tid >> 6;
  const int qq = l & 15, g = l >> 4;
  const int row = tid >> 2, gp = tid & 3;
  f32x4 acc[4] = {};
  for (int ks = 0; ks < 8; ++ks) {
    bf16x8 av = *(const bf16x8*)(o_g + (size_t)(Mbase + row) * 256 + ks * 32 + gp * 8);
    const float* wsrc = Wo + (size_t)(Nbase + row) * 256 + ks * 32 + gp * 8;
    f32x4 w0 = *(const f32x4*)wsrc;
    f32x4 w1 = *(const f32x4*)(wsrc + 4);
    U8 uw;
    uw.u[0] = pack2bf(w0[0], w0[1]); uw.u[1] = pack2bf(w0[2], w0[3]);
    uw.u[2] = pack2bf(w1[0], w1[1]); uw.u[3] = pack2bf(w1[2], w1[3]);
    __syncthreads();
    *(bf16x8*)((char*)sA + swz64(row, gp)) = av;
    *(bf16x8*)((char*)sB + swz64(row, gp)) = uw.v;
    __syncthreads();
    bf16x8 a = *(bf16x8*)((char*)sA + swz64(w * 16 + qq, g));
#pragma unroll
    for (int nf = 0; nf < 4; ++nf) {
      bf16x8 bb = *(bf16x8*)((char*)sB + swz64(nf * 16 + qq, g));
      acc[nf] = mfma32(a, bb, acc[nf]);
    }
  }
#pragma unroll
  for (int nf = 0; nf < 4; ++nf) {
    int n = Nbase + nf * 16 + qq;
    float bias = bo[n];
#pragma unroll
    for (int r = 0; r < 4; ++r) {
      int m = Mbase + w * 16 + 4 * g + r;
      out[(size_t)m * NC + n] = acc[nf][r] + bias;
    }
  }
}

extern "C" void kernel_launch(void* const* d_in, const int* in_sizes, int n_in,
                              void* d_out, int out_size, void* d_ws, size_t ws_size,
                              hipStream_t stream) {
  (void)in_sizes; (void)n_in; (void)out_size; (void)ws_size;
  const float* qx        = (const float*)d_in[0];
  const float* kvx       = (const float*)d_in[1];
  const float* bias_mask = (const float*)d_in[2];
  const float* bias_pair = (const float*)d_in[3];
  const float* Wq        = (const float*)d_in[4];
  const float* Wk        = (const float*)d_in[5];
  const float* Wv        = (const float*)d_in[6];
  const float* Wo        = (const float*)d_in[7];
  const float* bo        = (const float*)d_in[8];
  const float* Wg        = (const float*)d_in[9];
  const float* bg        = (const float*)d_in[10];

  char* ws = (char*)d_ws;
  uint16_t* q_p  = (uint16_t*)(ws);                       // 2 MB
  uint16_t* k_p  = (uint16_t*)(ws + (2u << 20));          // 2 MB
  uint16_t* v_p  = (uint16_t*)(ws + (4u << 20));          // 2 MB  [B,H,D,K]
  float*    g_ws = (float*)   (ws + (6u << 20));          // 4 MB
  uint16_t* o_g  = (uint16_t*)(ws + (10u << 20));         // 2 MB
  float* out = (float*)d_out;

  proj_kernel<<<dim3(1024), dim3(256), 0, stream>>>(qx, kvx, Wq, Wk, Wv, Wg, bg,
                                                    q_p, k_p, v_p, g_ws);
  attn_kernel<<<dim3(512), dim3(256), 0, stream>>>(q_p, k_p, v_p, bias_mask,
                                                   bias_pair, g_ws, o_g);
  outproj_kernel<<<dim3(256), dim3(256), 0, stream>>>(o_g, Wo, bo, out);
}